// Round 3
// baseline (216.502 us; speedup 1.0000x reference)
//
#include <hip/hip_runtime.h>

namespace {
constexpr int B = 16, C = 128, H = 64, W = 64;
constexpr int HEADS = 4, HD = 32;
constexpr float SCALE = 0.17677669529663687f; // 32^-0.5

// Block = half-row (32 px) x 4 heads x 2 channel-halves.
// wave = head; lane = (chhalf<<5)|wl; thread owns 16 of the head's 32 channels.
// Logit partials combined cross-half with one __shfl_xor(.,32).
__global__ __launch_bounds__(256, 8) void dilate_attn(
    const float* __restrict__ q, const float* __restrict__ k,
    const float* __restrict__ v, float* __restrict__ out) {
  __shared__ float4 smem[32 * 32];  // 32 px x 32 float4-chunks (=128 ch) = 16 KB

  const int tid  = threadIdx.x;
  const int wl   = tid & 31;
  const int hf   = (tid >> 5) & 1;  // channel half
  const int head = tid >> 6;        // wave index = head

  // XCD swizzle: blockIdx%8 -> XCD; each XCD owns 2 images, rows in order ->
  // rolling 5-row k/v halo window stays in that XCD's L2.
  const int blk  = blockIdx.x;
  const int xcd  = blk & 7;
  const int slot = blk >> 3;            // 0..255
  const int b    = xcd * 2 + (slot >> 7);
  const int rh   = slot & 127;
  const int h    = rh >> 1;
  const int w    = ((rh & 1) << 5) | wl;

  const size_t plane = (size_t)H * W;  // 4096
  const size_t cbase = ((size_t)b * C + head * HD + hf * 16) * plane;
  const float* qp = q + cbase + (size_t)h * W + w;
  const float* kp = k + cbase;
  const float* vp = v + cbase;

  // 9 dilated taps; OOB -> clamped offset + zero mask (branchless)
  int   offs[9];
  float mask[9];
  #pragma unroll
  for (int iy = 0; iy < 3; ++iy) {
    #pragma unroll
    for (int jx = 0; jx < 3; ++jx) {
      const int kk = iy * 3 + jx;
      const int hh = h + 2 * (iy - 1);
      const int ww = w + 2 * (jx - 1);
      const bool ok = ((unsigned)hh < (unsigned)H) && ((unsigned)ww < (unsigned)W);
      offs[kk] = ok ? hh * W + ww : 0;
      mask[kk] = ok ? 1.0f : 0.0f;
    }
  }

  // ---- Phase 1: partial logits over this thread's 16 channels ----
  float l[9];
  #pragma unroll
  for (int kk = 0; kk < 9; ++kk) l[kk] = 0.0f;

  #pragma unroll
  for (int dg = 0; dg < 8; ++dg) {     // 2 ch per iter
    float qd[2], kd[2][9];
    #pragma unroll
    for (int di = 0; di < 2; ++di) {
      const int d = dg * 2 + di;
      qd[di] = qp[d * plane];
      const float* kc = kp + d * plane;
      #pragma unroll
      for (int kk = 0; kk < 9; ++kk) kd[di][kk] = kc[offs[kk]];
    }
    #pragma unroll
    for (int di = 0; di < 2; ++di)
      #pragma unroll
      for (int kk = 0; kk < 9; ++kk) l[kk] = fmaf(qd[di], kd[di][kk], l[kk]);
  }

  // cross-half combine: partner lane = lane ^ 32 (same wave)
  #pragma unroll
  for (int kk = 0; kk < 9; ++kk) l[kk] += __shfl_xor(l[kk], 32, 64);

  // ---- Phase 2: softmax over 9 (zero-padded keys keep logit 0 in denom) ----
  float m = -1e30f;
  #pragma unroll
  for (int kk = 0; kk < 9; ++kk) {
    l[kk] *= mask[kk];
    m = fmaxf(m, l[kk]);
  }
  float p[9], s = 0.0f;
  #pragma unroll
  for (int kk = 0; kk < 9; ++kk) {
    p[kk] = __expf((l[kk] - m) * SCALE);
    s += p[kk];
  }
  const float r = 1.0f / s;
  #pragma unroll
  for (int kk = 0; kk < 9; ++kk) p[kk] *= r * mask[kk];  // fold V zero-pad

  // ---- Phase 3: PV over this thread's 16 channels; stage in LDS ----
  #pragma unroll
  for (int dg4 = 0; dg4 < 4; ++dg4) {   // one float4 chunk per iter
    float o[4] = {0, 0, 0, 0};
    #pragma unroll
    for (int half = 0; half < 2; ++half) {
      float vd[2][9];
      #pragma unroll
      for (int di = 0; di < 2; ++di) {
        const float* vc = vp + (dg4 * 4 + half * 2 + di) * plane;
        #pragma unroll
        for (int kk = 0; kk < 9; ++kk) vd[di][kk] = vc[offs[kk]];
      }
      #pragma unroll
      for (int di = 0; di < 2; ++di)
        #pragma unroll
        for (int kk = 0; kk < 9; ++kk)
          o[half * 2 + di] = fmaf(p[kk], vd[di][kk], o[half * 2 + di]);
    }
    const int c4 = head * 8 + hf * 4 + dg4;   // float4-chunk index 0..31
    smem[(wl << 5) | (c4 ^ wl)] = make_float4(o[0], o[1], o[2], o[3]);
  }

  __syncthreads();

  // ---- Coalesced store: 16 KB contiguous block region ----
  float4* outp = (float4*)(out + ((size_t)(b * H + h) * W + ((rh & 1) << 5)) * C);
  #pragma unroll
  for (int it = 0; it < 4; ++it) {
    const int L = it * 256 + tid;
    const int px = L >> 5, c = L & 31;
    outp[L] = smem[(px << 5) | (c ^ px)];
  }
}
} // namespace

extern "C" void kernel_launch(void* const* d_in, const int* in_sizes, int n_in,
                              void* d_out, int out_size, void* d_ws, size_t ws_size,
                              hipStream_t stream) {
  const float* q = (const float*)d_in[0];
  const float* k = (const float*)d_in[1];
  const float* v = (const float*)d_in[2];
  float* o = (float*)d_out;
  dilate_attn<<<dim3(2048), dim3(256), 0, stream>>>(q, k, v, o);
}

// Round 4
// 159.551 us; speedup vs baseline: 1.3570x; 1.3570x over previous
//
#include <hip/hip_runtime.h>

namespace {
constexpr int B = 16, C = 128, H = 64, W = 64;
constexpr int HEADS = 4, HD = 32;
constexpr float SCALE = 0.17677669529663687f; // 32^-0.5

// Block = half-row (32 px) x 4 heads x 2 channel-halves; 2048 blocks.
// wave = head; lane = (chhalf<<5)|wl; thread owns 16 of the head's 32 channels.
// Logit partials combined cross-half with one __shfl_xor(.,32).
// launch_bounds(256,4): 128-VGPR cap -- R3's (256,8)=64-cap spilled to scratch
// (VGPR=32, WRITE_SIZE 100 MB). At ~60 VGPR the HW still reaches 8 waves/SIMD.
__global__ __launch_bounds__(256, 4) void dilate_attn(
    const float* __restrict__ q, const float* __restrict__ k,
    const float* __restrict__ v, float* __restrict__ out) {
  __shared__ float4 smem[32 * 32];  // 32 px x 32 float4-chunks (=128 ch) = 16 KB

  const int tid  = threadIdx.x;
  const int wl   = tid & 31;
  const int hf   = (tid >> 5) & 1;  // channel half
  const int head = tid >> 6;        // wave index = head

  // XCD swizzle: blockIdx%8 -> XCD; each XCD owns 2 images, rows in order ->
  // rolling 5-row k/v halo window stays in that XCD's L2.
  const int blk  = blockIdx.x;
  const int xcd  = blk & 7;
  const int slot = blk >> 3;            // 0..255
  const int b    = xcd * 2 + (slot >> 7);
  const int rh   = slot & 127;
  const int h    = rh >> 1;
  const int w    = ((rh & 1) << 5) | wl;

  const size_t plane = (size_t)H * W;  // 4096
  const size_t cbase = ((size_t)b * C + head * HD + hf * 16) * plane;
  const float* qp = q + cbase + (size_t)h * W + w;
  const float* kp = k + cbase;
  const float* vp = v + cbase;

  // 9 dilated taps; OOB -> clamped offset + zero mask (branchless)
  int   offs[9];
  float mask[9];
  #pragma unroll
  for (int iy = 0; iy < 3; ++iy) {
    #pragma unroll
    for (int jx = 0; jx < 3; ++jx) {
      const int kk = iy * 3 + jx;
      const int hh = h + 2 * (iy - 1);
      const int ww = w + 2 * (jx - 1);
      const bool ok = ((unsigned)hh < (unsigned)H) && ((unsigned)ww < (unsigned)W);
      offs[kk] = ok ? hh * W + ww : 0;
      mask[kk] = ok ? 1.0f : 0.0f;
    }
  }

  // ---- Phase 1: partial logits over this thread's 16 channels ----
  float l[9];
  #pragma unroll
  for (int kk = 0; kk < 9; ++kk) l[kk] = 0.0f;

  #pragma unroll
  for (int dg = 0; dg < 8; ++dg) {     // 2 ch per iter
    float qd[2], kd[2][9];
    #pragma unroll
    for (int di = 0; di < 2; ++di) {
      const int d = dg * 2 + di;
      qd[di] = qp[d * plane];
      const float* kc = kp + d * plane;
      #pragma unroll
      for (int kk = 0; kk < 9; ++kk) kd[di][kk] = kc[offs[kk]];
    }
    #pragma unroll
    for (int di = 0; di < 2; ++di)
      #pragma unroll
      for (int kk = 0; kk < 9; ++kk) l[kk] = fmaf(qd[di], kd[di][kk], l[kk]);
  }

  // cross-half combine: partner lane = lane ^ 32 (same wave, same pixel/head)
  #pragma unroll
  for (int kk = 0; kk < 9; ++kk) l[kk] += __shfl_xor(l[kk], 32, 64);

  // ---- Phase 2: softmax over 9 (zero-padded keys keep logit 0 in denom) ----
  float m = -1e30f;
  #pragma unroll
  for (int kk = 0; kk < 9; ++kk) {
    l[kk] *= mask[kk];
    m = fmaxf(m, l[kk]);
  }
  float p[9], s = 0.0f;
  #pragma unroll
  for (int kk = 0; kk < 9; ++kk) {
    p[kk] = __expf((l[kk] - m) * SCALE);
    s += p[kk];
  }
  const float r = 1.0f / s;
  #pragma unroll
  for (int kk = 0; kk < 9; ++kk) p[kk] *= r * mask[kk];  // fold V zero-pad

  // ---- Phase 3: PV over this thread's 16 channels; stage in LDS ----
  #pragma unroll
  for (int dg4 = 0; dg4 < 4; ++dg4) {   // one float4 chunk per iter
    float o[4] = {0, 0, 0, 0};
    #pragma unroll
    for (int half = 0; half < 2; ++half) {
      float vd[2][9];
      #pragma unroll
      for (int di = 0; di < 2; ++di) {
        const float* vc = vp + (dg4 * 4 + half * 2 + di) * plane;
        #pragma unroll
        for (int kk = 0; kk < 9; ++kk) vd[di][kk] = vc[offs[kk]];
      }
      #pragma unroll
      for (int di = 0; di < 2; ++di)
        #pragma unroll
        for (int kk = 0; kk < 9; ++kk)
          o[half * 2 + di] = fmaf(p[kk], vd[di][kk], o[half * 2 + di]);
    }
    const int c4 = head * 8 + hf * 4 + dg4;   // float4-chunk index 0..31
    smem[(wl << 5) | (c4 ^ wl)] = make_float4(o[0], o[1], o[2], o[3]);
  }

  __syncthreads();

  // ---- Coalesced store: 16 KB contiguous block region ----
  float4* outp = (float4*)(out + ((size_t)(b * H + h) * W + ((rh & 1) << 5)) * C);
  #pragma unroll
  for (int it = 0; it < 4; ++it) {
    const int L = it * 256 + tid;
    const int px = L >> 5, c = L & 31;
    outp[L] = smem[(px << 5) | (c ^ px)];
  }
}
} // namespace

extern "C" void kernel_launch(void* const* d_in, const int* in_sizes, int n_in,
                              void* d_out, int out_size, void* d_ws, size_t ws_size,
                              hipStream_t stream) {
  const float* q = (const float*)d_in[0];
  const float* k = (const float*)d_in[1];
  const float* v = (const float*)d_in[2];
  float* o = (float*)d_out;
  dilate_attn<<<dim3(2048), dim3(256), 0, stream>>>(q, k, v, o);
}